// Round 1
// baseline (529.878 us; speedup 1.0000x reference)
//
#include <hip/hip_runtime.h>
#include <hip/hip_bf16.h>
#include <stdint.h>

#define E_    8
#define CAP_  2048
#define D_    1024
#define H_    4096

typedef unsigned short u16;
typedef __attribute__((ext_vector_type(8))) short bf16x8;   // 8 bf16 in 4 VGPRs
typedef __attribute__((ext_vector_type(4))) float f32x4;

__device__ __forceinline__ u16 f2bf(float f) {
    union { float f; unsigned int u; } v; v.f = f;
    unsigned int u = v.u;
    unsigned int r = (u + 0x7fffu + ((u >> 16) & 1u)) >> 16;   // round-nearest-even
    return (u16)r;
}

__device__ __forceinline__ void gload_lds16(const void* g, void* l) {
    __builtin_amdgcn_global_load_lds(
        (const __attribute__((address_space(1))) unsigned int*)g,
        (__attribute__((address_space(3))) unsigned int*)l,
        16, 0, 0);
}

// ---------------- fp32 -> bf16 elementwise convert (vectorized) ----------------
__global__ void cvt_f32_bf16(const float* __restrict__ in, u16* __restrict__ out, int n4) {
    int i = blockIdx.x * blockDim.x + threadIdx.x;
    if (i >= n4) return;
    const float4 v = ((const float4*)in)[i];
    ushort4 o;
    o.x = f2bf(v.x); o.y = f2bf(v.y); o.z = f2bf(v.z); o.w = f2bf(v.w);
    ((ushort4*)out)[i] = o;
}

// ---------------- W2 [E][H][D] fp32 -> W2T [E][D][H] bf16 ----------------
__global__ void transpose_cvt(const float* __restrict__ in, u16* __restrict__ out) {
    __shared__ float t[32][33];
    const int e  = blockIdx.z;
    const int h0 = blockIdx.y * 32;
    const int d0 = blockIdx.x * 32;
    const float* I = in + (size_t)e * H_ * D_;
    u16* O = out + (size_t)e * D_ * H_;
    const int tx = threadIdx.x, ty = threadIdx.y;
    t[ty][tx] = I[(size_t)(h0 + ty) * D_ + d0 + tx];
    __syncthreads();
    O[(size_t)(d0 + ty) * H_ + h0 + tx] = f2bf(t[tx][ty]);
}

// ---------------- bf16 B^T GEMM: C[M,N] = A[M,K] * B[N,K]^T + bias ----------------
// EPI 0: bias + relu, bf16 out (for y1).  EPI 1: bias, fp32 out.
template<int EPI>
__global__ __launch_bounds__(256, 2) void gemm_bt(
    const u16* __restrict__ A, const u16* __restrict__ B,
    const float* __restrict__ bias, void* __restrict__ Cv,
    int M, int N, int K,                       // lda = ldb = K, ldc = N
    size_t sA, size_t sB, size_t sBias, size_t sC)
{
    __shared__ __align__(16) u16 As[128 * 64];
    __shared__ __align__(16) u16 Bs[128 * 64];

    const int e = blockIdx.z;
    const u16* Ae = A + (size_t)e * sA;
    const u16* Be = B + (size_t)e * sB;
    const float* be = bias + (size_t)e * sBias;

    const int tid  = threadIdx.x;
    const int lane = tid & 63;
    const int wave = tid >> 6;        // 4 waves, 2x2 -> each owns 64x64
    const int wr   = wave >> 1;
    const int wc   = wave & 1;
    const int row0 = blockIdx.y * 128;
    const int col0 = blockIdx.x * 128;
    const int sr   = tid >> 3;        // staging row within 32-row chunk
    const int sc   = (tid & 7) * 8;   // staging col (8 bf16 = 16B)
    const int fr   = lane & 15;       // frag row (A) / col (B)
    const int fq   = lane >> 4;       // frag k-quadrant

    f32x4 acc[4][4] = {};

    const int nkt = K >> 6;           // BK = 64
    for (int kt = 0; kt < nkt; ++kt) {
        const int k0 = kt << 6;
        #pragma unroll
        for (int i = 0; i < 4; ++i) {
            const int r = i * 32 + sr;
            gload_lds16(Ae + (size_t)(row0 + r) * K + (k0 + sc), &As[i * 2048 + wave * 512]);
        }
        #pragma unroll
        for (int i = 0; i < 4; ++i) {
            const int r = i * 32 + sr;
            gload_lds16(Be + (size_t)(col0 + r) * K + (k0 + sc), &Bs[i * 2048 + wave * 512]);
        }
        __syncthreads();
        #pragma unroll
        for (int kk = 0; kk < 2; ++kk) {
            bf16x8 a[4], b[4];
            #pragma unroll
            for (int m = 0; m < 4; ++m)
                a[m] = *(const bf16x8*)&As[(wr * 64 + m * 16 + fr) * 64 + kk * 32 + fq * 8];
            #pragma unroll
            for (int n = 0; n < 4; ++n)
                b[n] = *(const bf16x8*)&Bs[(wc * 64 + n * 16 + fr) * 64 + kk * 32 + fq * 8];
            #pragma unroll
            for (int m = 0; m < 4; ++m)
                #pragma unroll
                for (int n = 0; n < 4; ++n)
                    acc[m][n] = __builtin_amdgcn_mfma_f32_16x16x32_bf16(a[m], b[n], acc[m][n], 0, 0, 0);
        }
        __syncthreads();
    }

    // epilogue: C/D frag layout col = lane&15, row = (lane>>4)*4 + reg
    #pragma unroll
    for (int n = 0; n < 4; ++n) {
        const int ccol = col0 + wc * 64 + n * 16 + fr;
        const float bv = be[ccol];
        #pragma unroll
        for (int m = 0; m < 4; ++m) {
            const int crow = row0 + wr * 64 + m * 16 + fq * 4;
            #pragma unroll
            for (int i = 0; i < 4; ++i) {
                float v = acc[m][n][i] + bv;
                if (EPI == 0) {
                    v = v > 0.f ? v : 0.f;
                    ((u16*)Cv + (size_t)e * sC)[(size_t)(crow + i) * N + ccol] = f2bf(v);
                } else {
                    ((float*)Cv + (size_t)e * sC)[(size_t)(crow + i) * N + ccol] = v;
                }
            }
        }
    }
}

extern "C" void kernel_launch(void* const* d_in, const int* in_sizes, int n_in,
                              void* d_out, int out_size, void* d_ws, size_t ws_size,
                              hipStream_t stream) {
    (void)in_sizes; (void)n_in; (void)out_size; (void)ws_size;
    const float* x     = (const float*)d_in[0];
    const float* fc1_w = (const float*)d_in[1];
    const float* fc1_b = (const float*)d_in[2];
    const float* fc2_w = (const float*)d_in[3];
    const float* fc2_b = (const float*)d_in[4];
    float* out = (float*)d_out;

    // workspace layout (ushorts): xbf | w1bf | w2t | y1  => 288 MiB total
    u16* xbf  = (u16*)d_ws;                                 // E*CAP*D
    u16* w1bf = xbf  + (size_t)E_ * CAP_ * D_;              // E*H*D
    u16* w2t  = w1bf + (size_t)E_ * H_ * D_;                // E*D*H (transposed)
    u16* y1   = w2t  + (size_t)E_ * D_ * H_;                // E*CAP*H

    {   // x -> bf16
        int n4 = E_ * CAP_ * D_ / 4;
        cvt_f32_bf16<<<n4 / 256, 256, 0, stream>>>(x, xbf, n4);
    }
    {   // W1 -> bf16
        int n4 = E_ * H_ * D_ / 4;
        cvt_f32_bf16<<<n4 / 256, 256, 0, stream>>>(fc1_w, w1bf, n4);
    }
    // W2 -> bf16 transposed [E][D][H]
    transpose_cvt<<<dim3(D_ / 32, H_ / 32, E_), dim3(32, 32), 0, stream>>>(fc2_w, w2t);

    // GEMM1: y1[e] = relu(x[e] @ W1[e]^T + b1)   (M=CAP, N=H, K=D)
    gemm_bt<0><<<dim3(H_ / 128, CAP_ / 128, E_), 256, 0, stream>>>(
        xbf, w1bf, fc1_b, y1, CAP_, H_, D_,
        (size_t)CAP_ * D_, (size_t)H_ * D_, (size_t)H_, (size_t)CAP_ * H_);

    // GEMM2: out[e] = y1[e] @ W2[e] + b2 = y1[e] @ W2T[e]^T + b2   (M=CAP, N=D, K=H)
    gemm_bt<1><<<dim3(D_ / 128, CAP_ / 128, E_), 256, 0, stream>>>(
        y1, w2t, fc2_b, out, CAP_, D_, H_,
        (size_t)CAP_ * H_, (size_t)D_ * H_, (size_t)D_, (size_t)CAP_ * D_);
}

// Round 2
// 437.071 us; speedup vs baseline: 1.2123x; 1.2123x over previous
//
#include <hip/hip_runtime.h>
#include <hip/hip_bf16.h>
#include <stdint.h>

#define E_    8
#define CAP_  2048
#define D_    1024
#define H_    4096

typedef unsigned short u16;
typedef __attribute__((ext_vector_type(8))) short bf16x8;   // 8 bf16 in 4 VGPRs
typedef __attribute__((ext_vector_type(4))) float f32x4;

__device__ __forceinline__ u16 f2bf(float f) {
    union { float f; unsigned int u; } v; v.f = f;
    unsigned int u = v.u;
    unsigned int r = (u + 0x7fffu + ((u >> 16) & 1u)) >> 16;   // round-nearest-even
    return (u16)r;
}

__device__ __forceinline__ void gload_lds16(const void* g, void* l) {
    __builtin_amdgcn_global_load_lds(
        (const __attribute__((address_space(1))) unsigned int*)g,
        (__attribute__((address_space(3))) unsigned int*)l,
        16, 0, 0);
}

// ---------------- fp32 -> bf16 elementwise convert (vectorized) ----------------
__global__ void cvt_f32_bf16(const float* __restrict__ in, u16* __restrict__ out, int n4) {
    int i = blockIdx.x * blockDim.x + threadIdx.x;
    if (i >= n4) return;
    const float4 v = ((const float4*)in)[i];
    ushort4 o;
    o.x = f2bf(v.x); o.y = f2bf(v.y); o.z = f2bf(v.z); o.w = f2bf(v.w);
    ((ushort4*)out)[i] = o;
}

// ---------------- W2 [E][H][D] fp32 -> W2T [E][D][H] bf16 ----------------
__global__ void transpose_cvt(const float* __restrict__ in, u16* __restrict__ out) {
    __shared__ float t[32][33];
    const int e  = blockIdx.z;
    const int h0 = blockIdx.y * 32;
    const int d0 = blockIdx.x * 32;
    const float* I = in + (size_t)e * H_ * D_;
    u16* O = out + (size_t)e * D_ * H_;
    const int tx = threadIdx.x, ty = threadIdx.y;
    t[ty][tx] = I[(size_t)(h0 + ty) * D_ + d0 + tx];
    __syncthreads();
    O[(size_t)(d0 + ty) * H_ + h0 + tx] = f2bf(t[tx][ty]);
}

// ---------------- 256x256x64 8-phase bf16 B^T GEMM ----------------
// C[M,N] = A[M,K] * B[N,K]^T + bias; EPI 0: +relu, bf16 out; EPI 1: fp32 out.
// 8 waves (2M x 4N), per-wave 128x64 output. LDS 128KiB: [db][A/B][half][128*64].
// st_16x32 swizzle both-sides: linear global_load_lds dest + pre-swizzled global
// source + swizzled ds_read addr. Counted vmcnt(4) at tile boundaries (lead-6
// half-tile pipeline, order B0,B1,A0,A1 - B is register-held after phase 0).
template<int EPI>
__global__ __launch_bounds__(512, 2) void gemm256(
    const u16* __restrict__ A, const u16* __restrict__ B,
    const float* __restrict__ bias, void* __restrict__ Cv,
    int M, int N, int K, int TM, int TN,
    size_t sA, size_t sB, size_t sBias, size_t sC)
{
    __shared__ __align__(16) u16 lds[2][2][2][128 * 64];   // 128 KiB

    // XCD-aware bijective swizzle (gridDim.x % 8 == 0 guaranteed by launch)
    const int nwg = gridDim.x;
    const int cpx = nwg >> 3;
    const int bid = blockIdx.x;
    const int wg  = (bid & 7) * cpx + (bid >> 3);
    const int tpe = TM * TN;
    const int e   = wg / tpe;
    const int rem = wg - e * tpe;
    const int tn  = rem / TM;        // tm inner: consecutive wg share B-panel
    const int tm  = rem - tn * TM;
    const int row0 = tm << 8;
    const int col0 = tn << 8;

    const u16* Ae = A + (size_t)e * sA;
    const u16* Be = B + (size_t)e * sB;

    const int tid  = threadIdx.x;
    const int lane = tid & 63;
    const int w    = tid >> 6;       // 8 waves
    const int wr   = w >> 2;         // 0..1  (M)
    const int wc   = w & 3;          // 0..3  (N)
    const int wcH  = wc >> 1;        // B half
    const int wcL  = wc & 1;
    const int fr   = lane & 15;
    const int fq   = lane >> 4;
    // swizzled per-lane read offset within a [128][64]-bf16 half (bytes):
    // row*128 + (fq*16 ^ ((row>>2)&1)<<5); (row>>2)&1 == (fr>>2)&1 for all frag rows
    const int loff = fr * 128 + ((fq * 16) ^ (((fr >> 2) & 1) << 5));
    // staging source chunk swizzle: logical chunk = dest chunk ^ (bit5?bit1)
    const int sl   = lane ^ ((lane & 32) >> 4);
    const int NT   = K >> 6;

    f32x4 acc[8][4] = {};

    // stage one 128x64 half-tile: 8 waves x 2 loads x 64 lanes x 16B = 16KB
    auto stageA = [&](int u, int hf) {
        if (u >= NT) return;
        u16* dst = &lds[u & 1][0][hf][0];
        const int k0 = u << 6;
        #pragma unroll
        for (int l = 0; l < 2; ++l) {
            const int bc = (w * 2 + l) << 6;    // dest base chunk (wave-uniform)
            const int a  = bc + sl;             // logical source chunk
            gload_lds16(Ae + (size_t)(row0 + (hf << 7) + (a >> 3)) * K + (k0 + ((a & 7) << 3)),
                        dst + bc * 8);
        }
    };
    auto stageB = [&](int u, int hf) {
        if (u >= NT) return;
        u16* dst = &lds[u & 1][1][hf][0];
        const int k0 = u << 6;
        #pragma unroll
        for (int l = 0; l < 2; ++l) {
            const int bc = (w * 2 + l) << 6;
            const int a  = bc + sl;
            gload_lds16(Be + (size_t)(col0 + (hf << 7) + (a >> 3)) * K + (k0 + ((a & 7) << 3)),
                        dst + bc * 8);
        }
    };

    // prologue: tile0 {B0,B1,A0,A1} + tile1 {B0,B1}  (12 loads/thread)
    stageB(0, 0); stageB(0, 1); stageA(0, 0); stageA(0, 1);
    stageB(1, 0); stageB(1, 1);
    asm volatile("s_waitcnt vmcnt(4)" ::: "memory");   // tile0 resident
    __builtin_amdgcn_s_barrier();
    asm volatile("" ::: "memory");

    for (int t = 0; t < NT; ++t) {
        const int db = t & 1;
        const char* Ah = (const char*)&lds[db][0][wr][0];
        const char* Bh = (const char*)&lds[db][1][wcH][0];
        bf16x8 b[4][2];
        #pragma unroll
        for (int p = 0; p < 4; ++p) {
            // ds-load register subtiles for this phase (tile t)
            bf16x8 a[2][2];
            #pragma unroll
            for (int mm = 0; mm < 2; ++mm)
                #pragma unroll
                for (int kk = 0; kk < 2; ++kk)
                    a[mm][kk] = *(const bf16x8*)(Ah + (2 * p + mm) * 2048 + kk * 64 + loff);
            if (p == 0) {
                #pragma unroll
                for (int n = 0; n < 4; ++n)
                    #pragma unroll
                    for (int kk = 0; kk < 2; ++kk)
                        b[n][kk] = *(const bf16x8*)(Bh + wcL * 8192 + n * 2048 + kk * 64 + loff);
            }
            // stage 1 half-tile, lead 6 (order: A0,A1 of t+1, then B0,B1 of t+2)
            if (p == 0)      stageA(t + 1, 0);
            else if (p == 1) stageA(t + 1, 1);
            else if (p == 2) stageB(t + 2, 0);
            else             stageB(t + 2, 1);

            __builtin_amdgcn_s_barrier();
            asm volatile("" ::: "memory");
            __builtin_amdgcn_s_setprio(1);
            #pragma unroll
            for (int kk = 0; kk < 2; ++kk)
                #pragma unroll
                for (int mm = 0; mm < 2; ++mm)
                    #pragma unroll
                    for (int n = 0; n < 4; ++n)
                        acc[2 * p + mm][n] = __builtin_amdgcn_mfma_f32_16x16x32_bf16(
                            a[mm][kk], b[n][kk], acc[2 * p + mm][n], 0, 0, 0);
            __builtin_amdgcn_s_setprio(0);
            if (p == 3) {
                if (t < NT - 2)       asm volatile("s_waitcnt vmcnt(4)" ::: "memory");
                else if (t == NT - 2) asm volatile("s_waitcnt vmcnt(0)" ::: "memory");
            }
            __builtin_amdgcn_s_barrier();
            asm volatile("" ::: "memory");
        }
    }

    // epilogue: C/D frag layout col = lane&15, row = (lane>>4)*4 + reg
    const float* be = bias + (size_t)e * sBias;
    #pragma unroll
    for (int n = 0; n < 4; ++n) {
        const int ccol = col0 + wc * 64 + n * 16 + fr;
        const float bv = be[ccol];
        #pragma unroll
        for (int m = 0; m < 8; ++m) {
            const int crow = row0 + wr * 128 + m * 16 + fq * 4;
            #pragma unroll
            for (int i = 0; i < 4; ++i) {
                float v = acc[m][n][i] + bv;
                if (EPI == 0) {
                    v = v > 0.f ? v : 0.f;
                    ((u16*)Cv + (size_t)e * sC)[(size_t)(crow + i) * N + ccol] = f2bf(v);
                } else {
                    ((float*)Cv + (size_t)e * sC)[(size_t)(crow + i) * N + ccol] = v;
                }
            }
        }
    }
}

extern "C" void kernel_launch(void* const* d_in, const int* in_sizes, int n_in,
                              void* d_out, int out_size, void* d_ws, size_t ws_size,
                              hipStream_t stream) {
    (void)in_sizes; (void)n_in; (void)out_size; (void)ws_size;
    const float* x     = (const float*)d_in[0];
    const float* fc1_w = (const float*)d_in[1];
    const float* fc1_b = (const float*)d_in[2];
    const float* fc2_w = (const float*)d_in[3];
    const float* fc2_b = (const float*)d_in[4];
    float* out = (float*)d_out;

    // workspace layout (ushorts): xbf | w1bf | w2t | y1  => 288 MiB total
    u16* xbf  = (u16*)d_ws;                                 // E*CAP*D
    u16* w1bf = xbf  + (size_t)E_ * CAP_ * D_;              // E*H*D
    u16* w2t  = w1bf + (size_t)E_ * H_ * D_;                // E*D*H (transposed)
    u16* y1   = w2t  + (size_t)E_ * D_ * H_;                // E*CAP*H

    {   // x -> bf16
        int n4 = E_ * CAP_ * D_ / 4;
        cvt_f32_bf16<<<n4 / 256, 256, 0, stream>>>(x, xbf, n4);
    }
    {   // W1 -> bf16
        int n4 = E_ * H_ * D_ / 4;
        cvt_f32_bf16<<<n4 / 256, 256, 0, stream>>>(fc1_w, w1bf, n4);
    }
    // W2 -> bf16 transposed [E][D][H]
    transpose_cvt<<<dim3(D_ / 32, H_ / 32, E_), dim3(32, 32), 0, stream>>>(fc2_w, w2t);

    // GEMM1: y1[e] = relu(x[e] @ W1[e]^T + b1)   (M=CAP, N=H, K=D)
    gemm256<0><<<dim3(E_ * (CAP_ / 256) * (H_ / 256)), 512, 0, stream>>>(
        xbf, w1bf, fc1_b, y1, CAP_, H_, D_, CAP_ / 256, H_ / 256,
        (size_t)CAP_ * D_, (size_t)H_ * D_, (size_t)H_, (size_t)CAP_ * H_);

    // GEMM2: out[e] = y1[e] @ W2T[e]^T + b2   (M=CAP, N=D, K=H)
    gemm256<1><<<dim3(E_ * (CAP_ / 256) * (D_ / 256)), 512, 0, stream>>>(
        y1, w2t, fc2_b, out, CAP_, D_, H_, CAP_ / 256, D_ / 256,
        (size_t)CAP_ * H_, (size_t)D_ * H_, (size_t)D_, (size_t)CAP_ * D_);
}

// Round 3
// 421.127 us; speedup vs baseline: 1.2582x; 1.0379x over previous
//
#include <hip/hip_runtime.h>
#include <hip/hip_bf16.h>
#include <stdint.h>

#define E_    8
#define CAP_  2048
#define D_    1024
#define H_    4096

typedef unsigned short u16;
typedef __attribute__((ext_vector_type(8))) short bf16x8;   // 8 bf16 in 4 VGPRs
typedef __attribute__((ext_vector_type(4))) float f32x4;

__device__ __forceinline__ u16 f2bf(float f) {
    union { float f; unsigned int u; } v; v.f = f;
    unsigned int u = v.u;
    unsigned int r = (u + 0x7fffu + ((u >> 16) & 1u)) >> 16;   // round-nearest-even
    return (u16)r;
}

__device__ __forceinline__ void gload_lds16(const void* g, void* l) {
    __builtin_amdgcn_global_load_lds(
        (const __attribute__((address_space(1))) unsigned int*)g,
        (__attribute__((address_space(3))) unsigned int*)l,
        16, 0, 0);
}

// ---------------- fp32 -> bf16 elementwise convert (vectorized) ----------------
__global__ void cvt_f32_bf16(const float* __restrict__ in, u16* __restrict__ out, int n4) {
    int i = blockIdx.x * blockDim.x + threadIdx.x;
    if (i >= n4) return;
    const float4 v = ((const float4*)in)[i];
    ushort4 o;
    o.x = f2bf(v.x); o.y = f2bf(v.y); o.z = f2bf(v.z); o.w = f2bf(v.w);
    ((ushort4*)out)[i] = o;
}

// ---------------- W2 [E][H][D] fp32 -> W2T [E][D][H] bf16 ----------------
__global__ void transpose_cvt(const float* __restrict__ in, u16* __restrict__ out) {
    __shared__ float t[32][33];
    const int e  = blockIdx.z;
    const int h0 = blockIdx.y * 32;
    const int d0 = blockIdx.x * 32;
    const float* I = in + (size_t)e * H_ * D_;
    u16* O = out + (size_t)e * D_ * H_;
    const int tx = threadIdx.x, ty = threadIdx.y;
    t[ty][tx] = I[(size_t)(h0 + ty) * D_ + d0 + tx];
    __syncthreads();
    O[(size_t)(d0 + ty) * H_ + h0 + tx] = f2bf(t[tx][ty]);
}

// ---------------- 256x256x64 8-phase bf16 B^T GEMM ----------------
// C[M,N] = A[M,K] * B[N,K]^T + bias; EPI 0: +relu, bf16 out; EPI 1: fp32 out.
// 8 waves (2M x 4N), per-wave 128x64 output. LDS 128KiB: [db][A/B][half][128*64].
// Full 3-bit XOR swizzle: physical col-chunk = logical col-chunk ^ (row&7).
// Write side: linear global_load_lds dest + pre-swizzled per-lane global source
// (sl = lane ^ ((lane>>3)&7), involution). Read side: col-chunk XOR (fr&7).
// Counted vmcnt(4) at tile boundary only (lead-6 half-tile pipeline, order
// A0,A1 of t+1 then B0,B1 of t+2; B is register-held after phase 0).
template<int EPI>
__global__ __launch_bounds__(512, 2) void gemm256(
    const u16* __restrict__ A, const u16* __restrict__ B,
    const float* __restrict__ bias, void* __restrict__ Cv,
    int M, int N, int K, int TM, int TN,
    size_t sA, size_t sB, size_t sBias, size_t sC)
{
    __shared__ __align__(16) u16 lds[2][2][2][128 * 64];   // 128 KiB

    // XCD-aware bijective swizzle (gridDim.x % 8 == 0 guaranteed by launch)
    const int nwg = gridDim.x;
    const int cpx = nwg >> 3;
    const int bid = blockIdx.x;
    const int wg  = (bid & 7) * cpx + (bid >> 3);
    const int tpe = TM * TN;
    const int e   = wg / tpe;
    const int rem = wg - e * tpe;
    const int tn  = rem / TM;        // tm inner: consecutive wg share B-panel
    const int tm  = rem - tn * TM;
    const int row0 = tm << 8;
    const int col0 = tn << 8;

    const u16* Ae = A + (size_t)e * sA;
    const u16* Be = B + (size_t)e * sB;

    const int tid  = threadIdx.x;
    const int lane = tid & 63;
    const int w    = tid >> 6;       // 8 waves
    const int wr   = w >> 2;         // 0..1  (M)
    const int wc   = w & 3;          // 0..3  (N)
    const int wcH  = wc >> 1;        // B half
    const int wcL  = wc & 1;
    const int fr   = lane & 15;
    const int fq   = lane >> 4;
    // swizzled per-lane read offsets within a [128][64]-bf16 half (bytes):
    // physical colbyte = (kk<<6) ^ ((fq ^ (fr&7))<<4); row contributes fr*128
    const int cx   = (fq ^ (fr & 7)) << 4;
    const int lo0  = fr * 128 + cx;          // kk = 0
    const int lo1  = fr * 128 + (cx ^ 64);   // kk = 1
    // staging: dest chunk = bc + lane (linear); logical source chunk-in-row =
    // (lane&7) ^ ((lane>>3)&7)  -> sl = lane ^ ((lane>>3)&7)
    const int sl   = lane ^ ((lane >> 3) & 7);
    const int NT   = K >> 6;

    f32x4 acc[8][4] = {};

    // stage one 128x64 half-tile: 8 waves x 2 loads x 64 lanes x 16B = 16KB
    auto stageA = [&](int u, int hf) {
        if (u >= NT) return;
        u16* dst = &lds[u & 1][0][hf][0];
        const int k0 = u << 6;
        #pragma unroll
        for (int l = 0; l < 2; ++l) {
            const int bc = (w * 2 + l) << 6;    // dest base chunk (wave-uniform)
            const int a  = bc + sl;             // logical source chunk
            gload_lds16(Ae + (size_t)(row0 + (hf << 7) + (a >> 3)) * K + (k0 + ((a & 7) << 3)),
                        dst + bc * 8);
        }
    };
    auto stageB = [&](int u, int hf) {
        if (u >= NT) return;
        u16* dst = &lds[u & 1][1][hf][0];
        const int k0 = u << 6;
        #pragma unroll
        for (int l = 0; l < 2; ++l) {
            const int bc = (w * 2 + l) << 6;
            const int a  = bc + sl;
            gload_lds16(Be + (size_t)(col0 + (hf << 7) + (a >> 3)) * K + (k0 + ((a & 7) << 3)),
                        dst + bc * 8);
        }
    };

    // prologue: tile0 {B0,B1,A0,A1} + tile1 {B0,B1}  (12 loads/thread)
    stageB(0, 0); stageB(0, 1); stageA(0, 0); stageA(0, 1);
    stageB(1, 0); stageB(1, 1);
    asm volatile("s_waitcnt vmcnt(4)");   // tile0 resident
    __builtin_amdgcn_s_barrier();

    for (int t = 0; t < NT; ++t) {
        const int db = t & 1;
        const char* Ah = (const char*)&lds[db][0][wr][0];
        const char* Bh = (const char*)&lds[db][1][wcH][0];
        bf16x8 b[4][2];
        #pragma unroll
        for (int p = 0; p < 4; ++p) {
            // ds-load register subtiles for this phase (tile t)
            bf16x8 a[2][2];
            #pragma unroll
            for (int mm = 0; mm < 2; ++mm) {
                a[mm][0] = *(const bf16x8*)(Ah + (2 * p + mm) * 2048 + lo0);
                a[mm][1] = *(const bf16x8*)(Ah + (2 * p + mm) * 2048 + lo1);
            }
            if (p == 0) {
                #pragma unroll
                for (int n = 0; n < 4; ++n) {
                    b[n][0] = *(const bf16x8*)(Bh + wcL * 8192 + n * 2048 + lo0);
                    b[n][1] = *(const bf16x8*)(Bh + wcL * 8192 + n * 2048 + lo1);
                }
            }
            // stage 1 half-tile, lead 6 (order: A0,A1 of t+1, then B0,B1 of t+2)
            if (p == 0)      stageA(t + 1, 0);
            else if (p == 1) stageA(t + 1, 1);
            else if (p == 2) stageB(t + 2, 0);
            else             stageB(t + 2, 1);

            __builtin_amdgcn_s_barrier();
            asm volatile("s_waitcnt lgkmcnt(0)");
            __builtin_amdgcn_s_setprio(1);
            #pragma unroll
            for (int kk = 0; kk < 2; ++kk)
                #pragma unroll
                for (int mm = 0; mm < 2; ++mm)
                    #pragma unroll
                    for (int n = 0; n < 4; ++n)
                        acc[2 * p + mm][n] = __builtin_amdgcn_mfma_f32_16x16x32_bf16(
                            a[mm][kk], b[n][kk], acc[2 * p + mm][n], 0, 0, 0);
            __builtin_amdgcn_s_setprio(0);
            if (p == 3) {
                if (t < NT - 2)       asm volatile("s_waitcnt vmcnt(4)");
                else if (t == NT - 2) asm volatile("s_waitcnt vmcnt(0)");
            }
            __builtin_amdgcn_s_barrier();
        }
    }

    // epilogue: C/D frag layout col = lane&15, row = (lane>>4)*4 + reg
    const float* be = bias + (size_t)e * sBias;
    #pragma unroll
    for (int n = 0; n < 4; ++n) {
        const int ccol = col0 + wc * 64 + n * 16 + fr;
        const float bv = be[ccol];
        #pragma unroll
        for (int m = 0; m < 8; ++m) {
            const int crow = row0 + wr * 128 + m * 16 + fq * 4;
            #pragma unroll
            for (int i = 0; i < 4; ++i) {
                float v = acc[m][n][i] + bv;
                if (EPI == 0) {
                    v = v > 0.f ? v : 0.f;
                    ((u16*)Cv + (size_t)e * sC)[(size_t)(crow + i) * N + ccol] = f2bf(v);
                } else {
                    ((float*)Cv + (size_t)e * sC)[(size_t)(crow + i) * N + ccol] = v;
                }
            }
        }
    }
}

extern "C" void kernel_launch(void* const* d_in, const int* in_sizes, int n_in,
                              void* d_out, int out_size, void* d_ws, size_t ws_size,
                              hipStream_t stream) {
    (void)in_sizes; (void)n_in; (void)out_size; (void)ws_size;
    const float* x     = (const float*)d_in[0];
    const float* fc1_w = (const float*)d_in[1];
    const float* fc1_b = (const float*)d_in[2];
    const float* fc2_w = (const float*)d_in[3];
    const float* fc2_b = (const float*)d_in[4];
    float* out = (float*)d_out;

    // workspace layout (ushorts): xbf | w1bf | w2t | y1  => 288 MiB total
    u16* xbf  = (u16*)d_ws;                                 // E*CAP*D
    u16* w1bf = xbf  + (size_t)E_ * CAP_ * D_;              // E*H*D
    u16* w2t  = w1bf + (size_t)E_ * H_ * D_;                // E*D*H (transposed)
    u16* y1   = w2t  + (size_t)E_ * D_ * H_;                // E*CAP*H

    {   // x -> bf16
        int n4 = E_ * CAP_ * D_ / 4;
        cvt_f32_bf16<<<n4 / 256, 256, 0, stream>>>(x, xbf, n4);
    }
    {   // W1 -> bf16
        int n4 = E_ * H_ * D_ / 4;
        cvt_f32_bf16<<<n4 / 256, 256, 0, stream>>>(fc1_w, w1bf, n4);
    }
    // W2 -> bf16 transposed [E][D][H]
    transpose_cvt<<<dim3(D_ / 32, H_ / 32, E_), dim3(32, 32), 0, stream>>>(fc2_w, w2t);

    // GEMM1: y1[e] = relu(x[e] @ W1[e]^T + b1)   (M=CAP, N=H, K=D)
    gemm256<0><<<dim3(E_ * (CAP_ / 256) * (H_ / 256)), 512, 0, stream>>>(
        xbf, w1bf, fc1_b, y1, CAP_, H_, D_, CAP_ / 256, H_ / 256,
        (size_t)CAP_ * D_, (size_t)H_ * D_, (size_t)H_, (size_t)CAP_ * H_);

    // GEMM2: out[e] = y1[e] @ W2T[e]^T + b2   (M=CAP, N=D, K=H)
    gemm256<1><<<dim3(E_ * (CAP_ / 256) * (D_ / 256)), 512, 0, stream>>>(
        y1, w2t, fc2_b, out, CAP_, D_, H_, CAP_ / 256, D_ / 256,
        (size_t)CAP_ * H_, (size_t)D_ * H_, (size_t)D_, (size_t)CAP_ * D_);
}

// Round 4
// 384.930 us; speedup vs baseline: 1.3766x; 1.0940x over previous
//
#include <hip/hip_runtime.h>
#include <hip/hip_bf16.h>
#include <stdint.h>

#define E_    8
#define CAP_  2048
#define D_    1024
#define H_    4096

typedef unsigned short u16;
typedef __attribute__((ext_vector_type(8))) short bf16x8;   // 8 bf16 in 4 VGPRs
typedef __attribute__((ext_vector_type(4))) float f32x4;

__device__ __forceinline__ u16 f2bf(float f) {
    union { float f; unsigned int u; } v; v.f = f;
    unsigned int u = v.u;
    unsigned int r = (u + 0x7fffu + ((u >> 16) & 1u)) >> 16;   // round-nearest-even
    return (u16)r;
}

__device__ __forceinline__ void gload_lds16(const void* g, void* l) {
    __builtin_amdgcn_global_load_lds(
        (const __attribute__((address_space(1))) unsigned int*)g,
        (__attribute__((address_space(3))) unsigned int*)l,
        16, 0, 0);
}

// ---------------- fp32 -> bf16 elementwise convert (vectorized) ----------------
__global__ void cvt_f32_bf16(const float* __restrict__ in, u16* __restrict__ out, int n4) {
    int i = blockIdx.x * blockDim.x + threadIdx.x;
    if (i >= n4) return;
    const float4 v = ((const float4*)in)[i];
    ushort4 o;
    o.x = f2bf(v.x); o.y = f2bf(v.y); o.z = f2bf(v.z); o.w = f2bf(v.w);
    ((ushort4*)out)[i] = o;
}

// ---------------- W2 [E][H][D] fp32 -> W2T [E][D][H] bf16 ----------------
__global__ void transpose_cvt(const float* __restrict__ in, u16* __restrict__ out) {
    __shared__ float t[32][33];
    const int e  = blockIdx.z;
    const int h0 = blockIdx.y * 32;
    const int d0 = blockIdx.x * 32;
    const float* I = in + (size_t)e * H_ * D_;
    u16* O = out + (size_t)e * D_ * H_;
    const int tx = threadIdx.x, ty = threadIdx.y;
    t[ty][tx] = I[(size_t)(h0 + ty) * D_ + d0 + tx];
    __syncthreads();
    O[(size_t)(d0 + ty) * H_ + h0 + tx] = f2bf(t[tx][ty]);
}

// ---------------- 256x256x64 8-phase bf16 B^T GEMM ----------------
// C[M,N] = A[M,K] * B[N,K]^T + bias; EPI 0: +relu, bf16 out; EPI 1: fp32 out.
// 8 waves (2M x 4N), per-wave 128x64 output. LDS 128KiB: [db][A/B][half][128*64].
// Full 3-bit XOR swizzle (0 bank conflicts, verified r3): physical col-chunk =
// logical col-chunk ^ (row&7); linear gload_lds dest + pre-swizzled global src.
// Counted vmcnt(4) at tile boundary only. Epilogue re-stages C through LDS for
// fully coalesced 16B/lane global stores (kills bf16 RMW write amplification).
template<int EPI>
__global__ __launch_bounds__(512, 2) void gemm256(
    const u16* __restrict__ A, const u16* __restrict__ B,
    const float* __restrict__ bias, void* __restrict__ Cv,
    int M, int N, int K, int TM, int TN,
    size_t sA, size_t sB, size_t sBias, size_t sC)
{
    __shared__ __align__(16) u16 lds[2][2][2][128 * 64];   // 128 KiB

    // XCD-aware bijective swizzle (gridDim.x % 8 == 0 guaranteed by launch)
    const int nwg = gridDim.x;
    const int cpx = nwg >> 3;
    const int bid = blockIdx.x;
    const int wg  = (bid & 7) * cpx + (bid >> 3);
    const int tpe = TM * TN;
    const int e   = wg / tpe;
    const int rem = wg - e * tpe;
    const int tn  = rem / TM;        // tm inner: consecutive wg share B-panel
    const int tm  = rem - tn * TM;
    const int row0 = tm << 8;
    const int col0 = tn << 8;

    const u16* Ae = A + (size_t)e * sA;
    const u16* Be = B + (size_t)e * sB;

    const int tid  = threadIdx.x;
    const int lane = tid & 63;
    const int w    = tid >> 6;       // 8 waves
    const int wr   = w >> 2;         // 0..1  (M)
    const int wc   = w & 3;          // 0..3  (N)
    const int wcH  = wc >> 1;        // B half
    const int wcL  = wc & 1;
    const int fr   = lane & 15;
    const int fq   = lane >> 4;
    // swizzled per-lane read offsets within a [128][64]-bf16 half (bytes):
    // physical colbyte = (kk<<6) ^ ((fq ^ (fr&7))<<4); row contributes fr*128
    const int cx   = (fq ^ (fr & 7)) << 4;
    const int lo0  = fr * 128 + cx;          // kk = 0
    const int lo1  = fr * 128 + (cx ^ 64);   // kk = 1
    // staging: dest chunk = bc + lane (linear); logical source chunk-in-row =
    // (lane&7) ^ ((lane>>3)&7)  -> sl = lane ^ ((lane>>3)&7)
    const int sl   = lane ^ ((lane >> 3) & 7);
    const int NT   = K >> 6;

    f32x4 acc[8][4] = {};

    // stage one 128x64 half-tile: 8 waves x 2 loads x 64 lanes x 16B = 16KB
    auto stageA = [&](int u, int hf) {
        if (u >= NT) return;
        u16* dst = &lds[u & 1][0][hf][0];
        const int k0 = u << 6;
        #pragma unroll
        for (int l = 0; l < 2; ++l) {
            const int bc = (w * 2 + l) << 6;    // dest base chunk (wave-uniform)
            const int a  = bc + sl;             // logical source chunk
            gload_lds16(Ae + (size_t)(row0 + (hf << 7) + (a >> 3)) * K + (k0 + ((a & 7) << 3)),
                        dst + bc * 8);
        }
    };
    auto stageB = [&](int u, int hf) {
        if (u >= NT) return;
        u16* dst = &lds[u & 1][1][hf][0];
        const int k0 = u << 6;
        #pragma unroll
        for (int l = 0; l < 2; ++l) {
            const int bc = (w * 2 + l) << 6;
            const int a  = bc + sl;
            gload_lds16(Be + (size_t)(col0 + (hf << 7) + (a >> 3)) * K + (k0 + ((a & 7) << 3)),
                        dst + bc * 8);
        }
    };

    // prologue: tile0 {B0,B1,A0,A1} + tile1 {B0,B1}  (12 loads/thread)
    stageB(0, 0); stageB(0, 1); stageA(0, 0); stageA(0, 1);
    stageB(1, 0); stageB(1, 1);
    asm volatile("s_waitcnt vmcnt(4)");   // tile0 resident
    __builtin_amdgcn_s_barrier();

    for (int t = 0; t < NT; ++t) {
        const int db = t & 1;
        const char* Ah = (const char*)&lds[db][0][wr][0];
        const char* Bh = (const char*)&lds[db][1][wcH][0];
        bf16x8 b[4][2];
        #pragma unroll
        for (int p = 0; p < 4; ++p) {
            // ds-load register subtiles for this phase (b first: first MFMA
            // operands complete earliest; compiler emits fine-grained lgkmcnt)
            if (p == 0) {
                #pragma unroll
                for (int n = 0; n < 4; ++n) {
                    b[n][0] = *(const bf16x8*)(Bh + wcL * 8192 + n * 2048 + lo0);
                    b[n][1] = *(const bf16x8*)(Bh + wcL * 8192 + n * 2048 + lo1);
                }
            }
            bf16x8 a[2][2];
            #pragma unroll
            for (int mm = 0; mm < 2; ++mm) {
                a[mm][0] = *(const bf16x8*)(Ah + (2 * p + mm) * 2048 + lo0);
                a[mm][1] = *(const bf16x8*)(Ah + (2 * p + mm) * 2048 + lo1);
            }
            // stage 1 half-tile, lead 6 (order: A0,A1 of t+1, then B0,B1 of t+2)
            if (p == 0)      stageA(t + 1, 0);
            else if (p == 1) stageA(t + 1, 1);
            else if (p == 2) stageB(t + 2, 0);
            else             stageB(t + 2, 1);

            __builtin_amdgcn_s_barrier();
            __builtin_amdgcn_s_setprio(1);
            #pragma unroll
            for (int kk = 0; kk < 2; ++kk)
                #pragma unroll
                for (int mm = 0; mm < 2; ++mm)
                    #pragma unroll
                    for (int n = 0; n < 4; ++n)
                        acc[2 * p + mm][n] = __builtin_amdgcn_mfma_f32_16x16x32_bf16(
                            a[mm][kk], b[n][kk], acc[2 * p + mm][n], 0, 0, 0);
            __builtin_amdgcn_s_setprio(0);
            if (p == 3) {
                if (t < NT - 2)       asm volatile("s_waitcnt vmcnt(4)");
                else if (t == NT - 2) asm volatile("s_waitcnt vmcnt(0)");
            }
            __builtin_amdgcn_s_barrier();
        }
    }

    // ---------------- coalesced epilogue via LDS re-staging ----------------
    // C/D frag layout: col = lane&15, row = (lane>>4)*4 + reg
    const float* be = bias + (size_t)e * sBias;
    if (EPI == 0) {
        // bf16 out: whole 256x256 tile as u16 -> 128 KiB, one pass
        u16* cl = (u16*)&lds[0][0][0][0];
        __builtin_amdgcn_s_barrier();
        #pragma unroll
        for (int n = 0; n < 4; ++n) {
            const int ccol = wc * 64 + n * 16 + fr;
            const float bv = be[col0 + ccol];
            #pragma unroll
            for (int m = 0; m < 8; ++m) {
                const int crow = wr * 128 + m * 16 + fq * 4;
                #pragma unroll
                for (int i = 0; i < 4; ++i) {
                    float v = acc[m][n][i] + bv;
                    v = v > 0.f ? v : 0.f;
                    cl[(crow + i) * 256 + ccol] = f2bf(v);
                }
            }
        }
        __builtin_amdgcn_s_barrier();
        u16* Ce = (u16*)Cv + (size_t)e * sC;
        const int rr = tid >> 5;           // 0..15
        const int cc = (tid & 31) * 8;     // u16 col, 16B granular
        #pragma unroll
        for (int s = 0; s < 16; ++s) {
            const int row = s * 16 + rr;
            const float4 v = *(const float4*)&cl[row * 256 + cc];
            *(float4*)&Ce[(size_t)(row0 + row) * N + col0 + cc] = v;
        }
    } else {
        // fp32 out: two passes of 128 rows (128 KiB each)
        float* cf = (float*)&lds[0][0][0][0];
        float* Ce = (float*)Cv + (size_t)e * sC;
        #pragma unroll
        for (int p = 0; p < 2; ++p) {
            __builtin_amdgcn_s_barrier();
            #pragma unroll
            for (int n = 0; n < 4; ++n) {
                const int ccol = wc * 64 + n * 16 + fr;
                const float bv = be[col0 + ccol];
                #pragma unroll
                for (int mm = 0; mm < 4; ++mm) {
                    const int lrow = wr * 64 + mm * 16 + fq * 4;
                    #pragma unroll
                    for (int i = 0; i < 4; ++i)
                        cf[(lrow + i) * 256 + ccol] = acc[p * 4 + mm][n][i] + bv;
                }
            }
            __builtin_amdgcn_s_barrier();
            const int lr = tid >> 6;          // 0..7
            const int cc = (tid & 63) * 4;    // f32 col, 16B granular
            #pragma unroll
            for (int s = 0; s < 16; ++s) {
                const int lrow = s * 8 + lr;
                const int wrr  = lrow >> 6;
                const int rem2 = lrow & 63;
                const int grow = row0 + wrr * 128 + p * 64 + rem2;
                const float4 v = *(const float4*)&cf[lrow * 256 + cc];
                *(float4*)&Ce[(size_t)grow * N + col0 + cc] = v;
            }
        }
    }
}

extern "C" void kernel_launch(void* const* d_in, const int* in_sizes, int n_in,
                              void* d_out, int out_size, void* d_ws, size_t ws_size,
                              hipStream_t stream) {
    (void)in_sizes; (void)n_in; (void)out_size; (void)ws_size;
    const float* x     = (const float*)d_in[0];
    const float* fc1_w = (const float*)d_in[1];
    const float* fc1_b = (const float*)d_in[2];
    const float* fc2_w = (const float*)d_in[3];
    const float* fc2_b = (const float*)d_in[4];
    float* out = (float*)d_out;

    // workspace layout (ushorts): xbf | w1bf | w2t | y1  => 288 MiB total
    u16* xbf  = (u16*)d_ws;                                 // E*CAP*D
    u16* w1bf = xbf  + (size_t)E_ * CAP_ * D_;              // E*H*D
    u16* w2t  = w1bf + (size_t)E_ * H_ * D_;                // E*D*H (transposed)
    u16* y1   = w2t  + (size_t)E_ * D_ * H_;                // E*CAP*H

    {   // x -> bf16
        int n4 = E_ * CAP_ * D_ / 4;
        cvt_f32_bf16<<<n4 / 256, 256, 0, stream>>>(x, xbf, n4);
    }
    {   // W1 -> bf16
        int n4 = E_ * H_ * D_ / 4;
        cvt_f32_bf16<<<n4 / 256, 256, 0, stream>>>(fc1_w, w1bf, n4);
    }
    // W2 -> bf16 transposed [E][D][H]
    transpose_cvt<<<dim3(D_ / 32, H_ / 32, E_), dim3(32, 32), 0, stream>>>(fc2_w, w2t);

    // GEMM1: y1[e] = relu(x[e] @ W1[e]^T + b1)   (M=CAP, N=H, K=D)
    gemm256<0><<<dim3(E_ * (CAP_ / 256) * (H_ / 256)), 512, 0, stream>>>(
        xbf, w1bf, fc1_b, y1, CAP_, H_, D_, CAP_ / 256, H_ / 256,
        (size_t)CAP_ * D_, (size_t)H_ * D_, (size_t)H_, (size_t)CAP_ * H_);

    // GEMM2: out[e] = y1[e] @ W2T[e]^T + b2   (M=CAP, N=D, K=H)
    gemm256<1><<<dim3(E_ * (CAP_ / 256) * (D_ / 256)), 512, 0, stream>>>(
        y1, w2t, fc2_b, out, CAP_, D_, H_, CAP_ / 256, D_ / 256,
        (size_t)CAP_ * H_, (size_t)D_ * H_, (size_t)D_, (size_t)CAP_ * D_);
}

// Round 5
// 342.972 us; speedup vs baseline: 1.5450x; 1.1223x over previous
//
#include <hip/hip_runtime.h>
#include <hip/hip_bf16.h>
#include <stdint.h>

#define E_    8
#define CAP_  2048
#define D_    1024
#define H_    4096

typedef unsigned short u16;
typedef __attribute__((ext_vector_type(8))) short bf16x8;   // 8 bf16 in 4 VGPRs
typedef __attribute__((ext_vector_type(4))) float f32x4;

__device__ __forceinline__ u16 f2bf(float f) {
    union { float f; unsigned int u; } v; v.f = f;
    unsigned int u = v.u;
    unsigned int r = (u + 0x7fffu + ((u >> 16) & 1u)) >> 16;   // round-nearest-even
    return (u16)r;
}

__device__ __forceinline__ void gload_lds16(const void* g, void* l) {
    __builtin_amdgcn_global_load_lds(
        (const __attribute__((address_space(1))) unsigned int*)g,
        (__attribute__((address_space(3))) unsigned int*)l,
        16, 0, 0);
}

// ---------------- fp32 -> bf16 elementwise convert (vectorized) ----------------
__global__ void cvt_f32_bf16(const float* __restrict__ in, u16* __restrict__ out, int n4) {
    int i = blockIdx.x * blockDim.x + threadIdx.x;
    if (i >= n4) return;
    const float4 v = ((const float4*)in)[i];
    ushort4 o;
    o.x = f2bf(v.x); o.y = f2bf(v.y); o.z = f2bf(v.z); o.w = f2bf(v.w);
    ((ushort4*)out)[i] = o;
}

// ---------------- W2 [E][H][D] fp32 -> W2T [E][D][H] bf16 (64x64 tiles) ----------------
__global__ void transpose_cvt(const float* __restrict__ in, u16* __restrict__ out) {
    __shared__ float t[64][69];
    const int e  = blockIdx.z;
    const int h0 = blockIdx.y * 64;
    const int d0 = blockIdx.x * 64;
    const float* I = in + (size_t)e * H_ * D_;
    u16* O = out + (size_t)e * D_ * H_;
    const int tid = threadIdx.x;
    const int r  = tid >> 4;          // 0..15
    const int c  = (tid & 15) * 4;    // 0..60
    #pragma unroll
    for (int s = 0; s < 4; ++s) {
        const int h = r + s * 16;
        const float4 v = *(const float4*)&I[(size_t)(h0 + h) * D_ + d0 + c];
        t[h][c] = v.x; t[h][c + 1] = v.y; t[h][c + 2] = v.z; t[h][c + 3] = v.w;
    }
    __syncthreads();
    #pragma unroll
    for (int s = 0; s < 4; ++s) {
        const int d = r + s * 16;
        ushort4 o;
        o.x = f2bf(t[c + 0][d]); o.y = f2bf(t[c + 1][d]);
        o.z = f2bf(t[c + 2][d]); o.w = f2bf(t[c + 3][d]);
        *(ushort4*)&O[(size_t)(d0 + d) * H_ + h0 + c] = o;
    }
}

// ---------------- 256x256x64 4-phase (1 barrier/phase) bf16 B^T GEMM ----------------
// C[M,N] = A[M,K] * B[N,K]^T + bias; EPI 0: +relu, bf16 out; EPI 1: fp32 out.
// 8 waves (2M x 4N), per-wave 128x64 output. LDS 128KiB: [db][A/B][half][128*64].
// Full 3-bit XOR swizzle (0 bank conflicts): physical col-chunk = logical ^ (row&7).
// ONE barrier per phase (post-MFMA): MFMA waits only own-wave ds_reads, so waves
// drift <=1 phase and LDS-read pipe overlaps MFMA pipe across waves. Race audit:
// b[] consumed by each wave's p0 MFMA before its barrier(p0); B(t+2) staging only
// after barrier(p1) >= all waves past p0. A(t+1) region unread this tile. Tile
// boundary protected by per-wave counted vmcnt(4) + barrier(p3).
template<int EPI>
__global__ __launch_bounds__(512, 2) void gemm256(
    const u16* __restrict__ A, const u16* __restrict__ B,
    const float* __restrict__ bias, void* __restrict__ Cv,
    int M, int N, int K, int TM, int TN,
    size_t sA, size_t sB, size_t sBias, size_t sC)
{
    __shared__ __align__(16) u16 lds[2][2][2][128 * 64];   // 128 KiB

    // XCD-aware bijective swizzle (gridDim.x % 8 == 0 guaranteed by launch)
    const int nwg = gridDim.x;
    const int cpx = nwg >> 3;
    const int bid = blockIdx.x;
    const int wg  = (bid & 7) * cpx + (bid >> 3);
    const int tpe = TM * TN;
    const int e   = wg / tpe;
    const int rem = wg - e * tpe;
    const int tn  = rem / TM;        // tm inner: consecutive wg share B-panel
    const int tm  = rem - tn * TM;
    const int row0 = tm << 8;
    const int col0 = tn << 8;

    const u16* Ae = A + (size_t)e * sA;
    const u16* Be = B + (size_t)e * sB;

    const int tid  = threadIdx.x;
    const int lane = tid & 63;
    const int w    = tid >> 6;       // 8 waves
    const int wr   = w >> 2;         // 0..1  (M)
    const int wc   = w & 3;          // 0..3  (N)
    const int wcH  = wc >> 1;        // B half
    const int wcL  = wc & 1;
    const int fr   = lane & 15;
    const int fq   = lane >> 4;
    // swizzled per-lane read offsets within a [128][64]-bf16 half (bytes)
    const int cx   = (fq ^ (fr & 7)) << 4;
    const int lo0  = fr * 128 + cx;          // kk = 0
    const int lo1  = fr * 128 + (cx ^ 64);   // kk = 1
    // staging source pre-swizzle (involution)
    const int sl   = lane ^ ((lane >> 3) & 7);
    const int NT   = K >> 6;

    // per-thread staging pointers, advanced +64 elems (128B) per staged tile
    const int srow = (w << 4) + (sl >> 3);   // + l*8 + hf*128
    const int scol = (sl & 7) << 3;
    const u16* pA[2][2];
    const u16* pB[2][2];
    #pragma unroll
    for (int l = 0; l < 2; ++l)
        #pragma unroll
        for (int hf = 0; hf < 2; ++hf) {
            pA[l][hf] = Ae + (size_t)(row0 + hf * 128 + srow + l * 8) * K + scol;
            pB[l][hf] = Be + (size_t)(col0 + hf * 128 + srow + l * 8) * K + scol;
        }

    auto stageA = [&](int buf, int hf, bool pred) {
        #pragma unroll
        for (int l = 0; l < 2; ++l) {
            if (pred) gload_lds16(pA[l][hf], &lds[buf][0][hf][(w * 2 + l) * 512]);
            pA[l][hf] += 64;
        }
    };
    auto stageB = [&](int buf, int hf, bool pred) {
        #pragma unroll
        for (int l = 0; l < 2; ++l) {
            if (pred) gload_lds16(pB[l][hf], &lds[buf][1][hf][(w * 2 + l) * 512]);
            pB[l][hf] += 64;
        }
    };

    f32x4 acc[8][4] = {};

    // prologue: tile0 {B,A} + tile1 {B}  (12 loads/thread); vmcnt(4) -> tile0 in
    stageB(0, 0, true); stageB(0, 1, true);
    stageA(0, 0, true); stageA(0, 1, true);
    stageB(1, 0, true); stageB(1, 1, true);
    asm volatile("s_waitcnt vmcnt(4)");
    __builtin_amdgcn_s_barrier();

    for (int t = 0; t < NT; ++t) {
        const int db = t & 1;
        const char* Ah = (const char*)&lds[db][0][wr][0];
        const char* Bh = (const char*)&lds[db][1][wcH][0];
        bf16x8 b[4][2];
        #pragma unroll
        for (int n = 0; n < 4; ++n) {
            b[n][0] = *(const bf16x8*)(Bh + wcL * 8192 + n * 2048 + lo0);
            b[n][1] = *(const bf16x8*)(Bh + wcL * 8192 + n * 2048 + lo1);
        }
        #pragma unroll
        for (int p = 0; p < 4; ++p) {
            bf16x8 a[2][2];
            #pragma unroll
            for (int mm = 0; mm < 2; ++mm) {
                a[mm][0] = *(const bf16x8*)(Ah + (2 * p + mm) * 2048 + lo0);
                a[mm][1] = *(const bf16x8*)(Ah + (2 * p + mm) * 2048 + lo1);
            }
            if (p == 0)      stageA(db ^ 1, 0, t + 1 < NT);
            else if (p == 1) stageA(db ^ 1, 1, t + 1 < NT);
            else if (p == 2) stageB(db,     0, t + 2 < NT);
            else             stageB(db,     1, t + 2 < NT);

            __builtin_amdgcn_s_setprio(1);
            #pragma unroll
            for (int kk = 0; kk < 2; ++kk)
                #pragma unroll
                for (int mm = 0; mm < 2; ++mm)
                    #pragma unroll
                    for (int n = 0; n < 4; ++n)
                        acc[2 * p + mm][n] = __builtin_amdgcn_mfma_f32_16x16x32_bf16(
                            a[mm][kk], b[n][kk], acc[2 * p + mm][n], 0, 0, 0);
            __builtin_amdgcn_s_setprio(0);
            if (p == 3) {
                if (t < NT - 2)       asm volatile("s_waitcnt vmcnt(4)");
                else if (t == NT - 2) asm volatile("s_waitcnt vmcnt(0)");
            }
            __builtin_amdgcn_s_barrier();
        }
    }

    // ---------------- coalesced epilogue via LDS re-staging ----------------
    // C/D frag layout: col = lane&15, row = (lane>>4)*4 + reg
    const float* be = bias + (size_t)e * sBias;
    if (EPI == 0) {
        // bf16 out: whole 256x256 tile as u16 -> 128 KiB, one pass
        u16* cl = (u16*)&lds[0][0][0][0];
        #pragma unroll
        for (int n = 0; n < 4; ++n) {
            const int ccol = wc * 64 + n * 16 + fr;
            const float bv = be[col0 + ccol];
            #pragma unroll
            for (int m = 0; m < 8; ++m) {
                const int crow = wr * 128 + m * 16 + fq * 4;
                #pragma unroll
                for (int i = 0; i < 4; ++i) {
                    float v = acc[m][n][i] + bv;
                    v = v > 0.f ? v : 0.f;
                    cl[(crow + i) * 256 + ccol] = f2bf(v);
                }
            }
        }
        __builtin_amdgcn_s_barrier();
        u16* Ce = (u16*)Cv + (size_t)e * sC;
        const int rr = tid >> 5;           // 0..15
        const int cc = (tid & 31) * 8;     // u16 col, 16B granular
        #pragma unroll
        for (int s = 0; s < 16; ++s) {
            const int row = s * 16 + rr;
            const float4 v = *(const float4*)&cl[row * 256 + cc];
            *(float4*)&Ce[(size_t)(row0 + row) * N + col0 + cc] = v;
        }
    } else {
        // fp32 out: two passes of 128 rows (128 KiB each)
        float* cf = (float*)&lds[0][0][0][0];
        float* Ce = (float*)Cv + (size_t)e * sC;
        #pragma unroll
        for (int p = 0; p < 2; ++p) {
            __builtin_amdgcn_s_barrier();
            #pragma unroll
            for (int n = 0; n < 4; ++n) {
                const int ccol = wc * 64 + n * 16 + fr;
                const float bv = be[col0 + ccol];
                #pragma unroll
                for (int mm = 0; mm < 4; ++mm) {
                    const int lrow = wr * 64 + mm * 16 + fq * 4;
                    #pragma unroll
                    for (int i = 0; i < 4; ++i)
                        cf[(lrow + i) * 256 + ccol] = acc[p * 4 + mm][n][i] + bv;
                }
            }
            __builtin_amdgcn_s_barrier();
            const int lr = tid >> 6;          // 0..7
            const int cc = (tid & 63) * 4;    // f32 col, 16B granular
            #pragma unroll
            for (int s = 0; s < 16; ++s) {
                const int lrow = s * 8 + lr;
                const int wrr  = lrow >> 6;
                const int rem2 = lrow & 63;
                const int grow = row0 + wrr * 128 + p * 64 + rem2;
                const float4 v = *(const float4*)&cf[lrow * 256 + cc];
                *(float4*)&Ce[(size_t)grow * N + col0 + cc] = v;
            }
        }
    }
}

extern "C" void kernel_launch(void* const* d_in, const int* in_sizes, int n_in,
                              void* d_out, int out_size, void* d_ws, size_t ws_size,
                              hipStream_t stream) {
    (void)in_sizes; (void)n_in; (void)out_size; (void)ws_size;
    const float* x     = (const float*)d_in[0];
    const float* fc1_w = (const float*)d_in[1];
    const float* fc1_b = (const float*)d_in[2];
    const float* fc2_w = (const float*)d_in[3];
    const float* fc2_b = (const float*)d_in[4];
    float* out = (float*)d_out;

    // workspace layout (ushorts): xbf | w1bf | w2t | y1  => 288 MiB total
    u16* xbf  = (u16*)d_ws;                                 // E*CAP*D
    u16* w1bf = xbf  + (size_t)E_ * CAP_ * D_;              // E*H*D
    u16* w2t  = w1bf + (size_t)E_ * H_ * D_;                // E*D*H (transposed)
    u16* y1   = w2t  + (size_t)E_ * D_ * H_;                // E*CAP*H

    {   // x -> bf16
        int n4 = E_ * CAP_ * D_ / 4;
        cvt_f32_bf16<<<n4 / 256, 256, 0, stream>>>(x, xbf, n4);
    }
    {   // W1 -> bf16
        int n4 = E_ * H_ * D_ / 4;
        cvt_f32_bf16<<<n4 / 256, 256, 0, stream>>>(fc1_w, w1bf, n4);
    }
    // W2 -> bf16 transposed [E][D][H]
    transpose_cvt<<<dim3(D_ / 64, H_ / 64, E_), 256, 0, stream>>>(fc2_w, w2t);

    // GEMM1: y1[e] = relu(x[e] @ W1[e]^T + b1)   (M=CAP, N=H, K=D)
    gemm256<0><<<dim3(E_ * (CAP_ / 256) * (H_ / 256)), 512, 0, stream>>>(
        xbf, w1bf, fc1_b, y1, CAP_, H_, D_, CAP_ / 256, H_ / 256,
        (size_t)CAP_ * D_, (size_t)H_ * D_, (size_t)H_, (size_t)CAP_ * H_);

    // GEMM2: out[e] = y1[e] @ W2T[e]^T + b2   (M=CAP, N=D, K=H)
    gemm256<1><<<dim3(E_ * (CAP_ / 256) * (D_ / 256)), 512, 0, stream>>>(
        y1, w2t, fc2_b, out, CAP_, D_, H_, CAP_ / 256, D_ / 256,
        (size_t)CAP_ * H_, (size_t)D_ * H_, (size_t)D_, (size_t)CAP_ * D_);
}